// Round 15
// baseline (40.890 us; speedup 1.0000x reference)
//
#include <hip/hip_runtime.h>
#include <math.h>

// SeesawLoss forward: B=8192 rows, C=4096 classes, P=0.8, Q=2.0, EPS=0.01
// Log-space algebra (no M2, no pass-3 transcendentals):
//   L    = logsumexp(o) ;  Koff = L + max(o_t - L, log(EPS))
//   g_j  = exp(o_j - Koff) (= sratio_j); exp(logit_j - Koff) = mit_j*max(g^3,g)
//   mit_j = min(powacc_j/powacc_t, 1)  [powacc = acc^0.8, monotone -> pred ok]
//   nll_b = Koff + log(Z) - o_t,  Z = sum_j mit_j*max(g_j^3, g_j)
// Range-safe: g <= 100 -> Z <= 4e9; Z >= g_t > 0. j==t term = g_t (mask-free).
//
// Per-row compute = R11 (best, 34.3us): 256 thr, 16 floats/thread in 4 named
// float4s, 2 barriers. THIS round: 8 rows per block (grid 1024 = 4 blocks/CU,
// one dispatch generation), ping-pong double-buffered row registers — row r+1
// loads issue at the top of row r's body and drain under its compute (cross-
// row software pipeline). Row scalars are block-uniform -> SGPRs. VGPR ~75
// under launch_bounds(256,4), far from R8's spill cliff. NO grid-wide atomics
// (R4/R5: same-address atomic+fence from 8192 blocks ~670us across 8 XCDs).

#define CC 4096
#define NR 8     // rows per block

__device__ __forceinline__ float wave_max(float v) {
    #pragma unroll
    for (int o = 32; o > 0; o >>= 1) v = fmaxf(v, __shfl_xor(v, o, 64));
    return v;
}
__device__ __forceinline__ float wave_sum(float v) {
    #pragma unroll
    for (int o = 32; o > 0; o >>= 1) v += __shfl_xor(v, o, 64);
    return v;
}

// exp each component against lane max (in place), return component sum
__device__ __forceinline__ float exp4(float4& v, float m) {
    v.x = __expf(v.x - m); v.y = __expf(v.y - m);
    v.z = __expf(v.z - m); v.w = __expf(v.w - m);
    return (v.x + v.y) + (v.z + v.w);
}

// pass-3 term sum for one float4 of e-values (8 VALU ops/element, no trans)
__device__ __forceinline__ float zsum4(float4 e, float4 pa, float rt, float c) {
    float gx = e.x * c, gy = e.y * c, gz = e.z * c, gw = e.w * c;
    float hx = fmaxf(gx * gx * gx, gx), hy = fmaxf(gy * gy * gy, gy);
    float hz = fmaxf(gz * gz * gz, gz), hw = fmaxf(gw * gw * gw, gw);
    float mx = fminf(pa.x * rt, 1.f),  my = fminf(pa.y * rt, 1.f);
    float mz = fminf(pa.z * rt, 1.f),  mw = fminf(pa.w * rt, 1.f);
    return (hx * mx + hy * my) + (hz * mz + hw * mw);
}

// One block: bincount via LDS atomics -> clamp -> powacc = acc^0.8 table.
__global__ __launch_bounds__(1024) void k_hist(const int* __restrict__ tg, int B,
                                               float* __restrict__ powacc) {
    __shared__ int hacc[CC];
    const int tid = threadIdx.x;
    #pragma unroll
    for (int k = 0; k < CC / 1024; ++k) hacc[tid + k * 1024] = 0;
    __syncthreads();
    const int4* __restrict__ tg4 = (const int4*)tg;
    for (int i = tid; i < B / 4; i += 1024) {
        int4 tv = tg4[i];
        atomicAdd(&hacc[tv.x], 1); atomicAdd(&hacc[tv.y], 1);
        atomicAdd(&hacc[tv.z], 1); atomicAdd(&hacc[tv.w], 1);
    }
    __syncthreads();
    #pragma unroll
    for (int k = 0; k < CC / 1024; ++k) {
        int i = tid + k * 1024;
        int a = hacc[i];
        if (a < 1) a = 1;                       // clamp(min=1)
        powacc[i] = __powf((float)a, 0.8f);     // acc^P
    }
}

// issue next row's 4 float4 loads into the ping-pong partner set
#define PRE_LOAD(U0, U1, U2, U3, RIDX) { \
    const float4* __restrict__ srcn = (const float4*)(outp + (size_t)(b0 + (RIDX)) * CC); \
    U0 = srcn[tid]; U1 = srcn[tid + 256]; U2 = srcn[tid + 512]; U3 = srcn[tid + 768]; }

// full per-row compute on register set A0..A3 (R11 body); PRE issues the
// next row's loads FIRST so they drain under this row's compute.
#define ROW_BODY(A0, A1, A2, A3, RIDX, PRE) { \
    const int   t_   = tg[b0 + (RIDX)];                       /* SGPR chain */ \
    const float ot_  = outp[(size_t)(b0 + (RIDX)) * CC + t_]; \
    const float pat_ = powacc[t_]; \
    PRE \
    float q0 = fmaxf(fmaxf(A0.x, A0.y), fmaxf(A0.z, A0.w)); \
    float q1 = fmaxf(fmaxf(A1.x, A1.y), fmaxf(A1.z, A1.w)); \
    float q2 = fmaxf(fmaxf(A2.x, A2.y), fmaxf(A2.z, A2.w)); \
    float q3 = fmaxf(fmaxf(A3.x, A3.y), fmaxf(A3.z, A3.w)); \
    const float mlane = fmaxf(fmaxf(q0, q1), fmaxf(q2, q3)); \
    const float mw = wave_max(mlane); \
    float s_ = (exp4(A0, mlane) + exp4(A1, mlane)) + (exp4(A2, mlane) + exp4(A3, mlane)); \
    float Sw = wave_sum(s_ * __expf(mlane - mw)); \
    if (lane0) red_ms[w] = make_float2(mw, Sw); \
    __syncthreads(); \
    const float M_ = fmaxf(fmaxf(red_ms[0].x, red_ms[1].x), fmaxf(red_ms[2].x, red_ms[3].x)); \
    const float S_ = red_ms[0].y * __expf(red_ms[0].x - M_) \
                   + red_ms[1].y * __expf(red_ms[1].x - M_) \
                   + red_ms[2].y * __expf(red_ms[2].x - M_) \
                   + red_ms[3].y * __expf(red_ms[3].x - M_); \
    const float L_   = M_ + __logf(S_); \
    const float Koff = L_ + fmaxf(ot_ - L_, LOG_EPS); \
    const float cf   = __expf(mlane - Koff); \
    const float rt_  = __fdividef(1.0f, pat_); \
    float z0 = zsum4(A0, pac[tid      ], rt_, cf); \
    float z1 = zsum4(A1, pac[tid + 256], rt_, cf); \
    float z2 = zsum4(A2, pac[tid + 512], rt_, cf); \
    float z3 = zsum4(A3, pac[tid + 768], rt_, cf); \
    float z_ = wave_sum((z0 + z1) + (z2 + z3)); \
    if (lane0) red_z[w] = z_; \
    __syncthreads(); \
    if (tid == 0) nll[b0 + (RIDX)] = Koff + __logf((red_z[0] + red_z[1]) + (red_z[2] + red_z[3])) - ot_; \
}

__global__ __launch_bounds__(256, 4) void k_row(const float* __restrict__ outp,
                                                const int* __restrict__ tg,
                                                const float* __restrict__ powacc,
                                                float* __restrict__ nll) {
    __shared__ float2 red_ms[4];
    __shared__ float  red_z[4];

    const int b0  = blockIdx.x * NR;
    const int tid = threadIdx.x;
    const int w   = tid >> 6;
    const bool lane0 = (tid & 63) == 0;

    const float LOG_EPS = -4.605170185988091f;   // log(0.01)
    const float4* __restrict__ pac = (const float4*)powacc;

    // prologue: row 0 into set a
    float4 a0, a1, a2, a3, u0, u1, u2, u3;
    PRE_LOAD(a0, a1, a2, a3, 0)

    // 8 rows, ping-pong a/u; each body prefetches the next row first
    ROW_BODY(a0, a1, a2, a3, 0, PRE_LOAD(u0, u1, u2, u3, 1))
    ROW_BODY(u0, u1, u2, u3, 1, PRE_LOAD(a0, a1, a2, a3, 2))
    ROW_BODY(a0, a1, a2, a3, 2, PRE_LOAD(u0, u1, u2, u3, 3))
    ROW_BODY(u0, u1, u2, u3, 3, PRE_LOAD(a0, a1, a2, a3, 4))
    ROW_BODY(a0, a1, a2, a3, 4, PRE_LOAD(u0, u1, u2, u3, 5))
    ROW_BODY(u0, u1, u2, u3, 5, PRE_LOAD(a0, a1, a2, a3, 6))
    ROW_BODY(a0, a1, a2, a3, 6, PRE_LOAD(u0, u1, u2, u3, 7))
    ROW_BODY(u0, u1, u2, u3, 7, )
}

// deterministic final mean: fixed strided partials + fixed tree
__global__ __launch_bounds__(1024) void k_reduce(const float* __restrict__ nll,
                                                 float* __restrict__ out, int B) {
    __shared__ float red[16];
    const int tid = threadIdx.x;
    const float4* __restrict__ n4 = (const float4*)nll;
    float s = 0.f;
    for (int i = tid; i < B / 4; i += 1024) {
        float4 v = n4[i];
        s += (v.x + v.y) + (v.z + v.w);
    }
    s = wave_sum(s);
    if ((tid & 63) == 0) red[tid >> 6] = s;
    __syncthreads();
    if (tid == 0) {
        float tsum = 0.f;
        #pragma unroll
        for (int k = 0; k < 16; ++k) tsum += red[k];
        out[0] = tsum / (float)B;
    }
}

extern "C" void kernel_launch(void* const* d_in, const int* in_sizes, int n_in,
                              void* d_out, int out_size, void* d_ws, size_t ws_size,
                              hipStream_t stream) {
    const float* outp = (const float*)d_in[0];   // [B, C] f32
    const int*   tg   = (const int*)d_in[1];     // [B] i32
    float*       out  = (float*)d_out;           // scalar f32

    const int B = in_sizes[1];                   // 8192 (C fixed at 4096)

    char*  ws     = (char*)d_ws;
    float* powacc = (float*)ws;                  // 16 KB
    float* nll    = (float*)(ws + 16384);        // B*4 = 32 KB

    k_hist  <<<1, 1024, 0, stream>>>(tg, B, powacc);
    k_row   <<<B / NR, 256, 0, stream>>>(outp, tg, powacc, nll);
    k_reduce<<<1, 1024, 0, stream>>>(nll, out, B);
}

// Round 16
// 34.565 us; speedup vs baseline: 1.1830x; 1.1830x over previous
//
#include <hip/hip_runtime.h>
#include <math.h>

// SeesawLoss forward: B=8192 rows, C=4096 classes, P=0.8, Q=2.0, EPS=0.01
// Full log-space algebra (no M2, no pass-3 transcendentals):
//   L    = logsumexp(o) ;  p_t = exp(o_t - L)
//   Koff = L + log(max(p_t, EPS))          (so g_j = exp(o_j-Koff) = sratio_j)
//   exp(logit_j - Koff) = mit_j * max(g_j^3, g_j)        [Q=2: comp=max(g^2,1)]
//   mit_j = min(powacc_j/powacc_t, 1)      [powacc = acc^0.8; x^0.8 monotone]
//   nll_b = Koff + log(Z) - o_t,  Z = sum_j mit_j*max(g_j^3, g_j)
// Range-safe: g <= exp(4.6) = 100 -> Z <= 4e9 (f32 ok); Z >= g_t > 0.
// At j==t: g_t <= 1 and mit_t = 1 -> term = g_t, matching the (1-onehot) mask.
//
// FINAL (= R11, best measured 34.3us): block-per-row, 256 threads, 16 floats/
// thread in 4 named float4s (rule #20: no addressable register arrays — R4/R8
// showed scratch demotion/spill), powacc prefetched with the row (8 loads in
// flight), wave-max on the DS pipe overlapping the exp burst, one rebase
// mul instead of per-merge-step exps. Structural lessons locked in:
//  - R4/R5: same-address device atomic + fence from 8192 blocks serializes
//    (~670us) across 8 non-coherent XCD L2s -> plain store + reduce kernel.
//  - R8/R12/R13: more data per thread or rows per block regresses (spill /
//    barrier payload); R15: cross-row pipelining at 4 blocks/CU regresses
//    (kills the inter-block TLP that hides latency). 8192 x 1-row blocks
//    with 32 waves/CU is the optimum at this size.

#define CC 4096

__device__ __forceinline__ float wave_max(float v) {
    #pragma unroll
    for (int o = 32; o > 0; o >>= 1) v = fmaxf(v, __shfl_xor(v, o, 64));
    return v;
}
__device__ __forceinline__ float wave_sum(float v) {
    #pragma unroll
    for (int o = 32; o > 0; o >>= 1) v += __shfl_xor(v, o, 64);
    return v;
}

// exp each component against lane max (in place), return component sum
__device__ __forceinline__ float exp4(float4& v, float m) {
    v.x = __expf(v.x - m); v.y = __expf(v.y - m);
    v.z = __expf(v.z - m); v.w = __expf(v.w - m);
    return (v.x + v.y) + (v.z + v.w);
}

// pass-3 term sum for one float4 of e-values (8 VALU ops/element, no trans)
__device__ __forceinline__ float zsum4(float4 e, float4 pa, float rt, float c) {
    float gx = e.x * c, gy = e.y * c, gz = e.z * c, gw = e.w * c;
    float hx = fmaxf(gx * gx * gx, gx), hy = fmaxf(gy * gy * gy, gy);
    float hz = fmaxf(gz * gz * gz, gz), hw = fmaxf(gw * gw * gw, gw);
    float mx = fminf(pa.x * rt, 1.f),  my = fminf(pa.y * rt, 1.f);
    float mz = fminf(pa.z * rt, 1.f),  mw = fminf(pa.w * rt, 1.f);
    return (hx * mx + hy * my) + (hz * mz + hw * mw);
}

// One block: bincount via LDS atomics -> clamp -> powacc = acc^0.8 table.
__global__ __launch_bounds__(1024) void k_hist(const int* __restrict__ tg, int B,
                                               float* __restrict__ powacc) {
    __shared__ int hacc[CC];
    const int tid = threadIdx.x;
    #pragma unroll
    for (int k = 0; k < CC / 1024; ++k) hacc[tid + k * 1024] = 0;
    __syncthreads();
    const int4* __restrict__ tg4 = (const int4*)tg;
    for (int i = tid; i < B / 4; i += 1024) {
        int4 tv = tg4[i];
        atomicAdd(&hacc[tv.x], 1); atomicAdd(&hacc[tv.y], 1);
        atomicAdd(&hacc[tv.z], 1); atomicAdd(&hacc[tv.w], 1);
    }
    __syncthreads();
    #pragma unroll
    for (int k = 0; k < CC / 1024; ++k) {
        int i = tid + k * 1024;
        int a = hacc[i];
        if (a < 1) a = 1;                       // clamp(min=1)
        powacc[i] = __powf((float)a, 0.8f);     // acc^P
    }
}

__global__ __launch_bounds__(256, 8) void k_row(const float* __restrict__ outp,
                                                const int* __restrict__ tg,
                                                const float* __restrict__ powacc,
                                                float* __restrict__ nll) {
    __shared__ float2 red_ms[4];
    __shared__ float  red_z[4];

    const int b   = blockIdx.x;
    const int tid = threadIdx.x;
    const int w   = tid >> 6;
    const bool lane0 = (tid & 63) == 0;

    const float LOG_EPS = -4.605170185988091f;   // log(0.01)

    // scalar chain early (critical path to Koff / rt)
    const int   t    = tg[b];
    const float o_t  = outp[(size_t)b * CC + t];
    const float pa_t = powacc[t];

    const float4* __restrict__ src = (const float4*)(outp + (size_t)b * CC);
    const float4* __restrict__ pac = (const float4*)powacc;

    // ---- all 8 loads issued together: row + powacc prefetch (rule #20 safe) ----
    float4 v0 = src[tid];
    float4 v1 = src[tid + 256];
    float4 v2 = src[tid + 512];
    float4 v3 = src[tid + 768];
    float4 pa0 = pac[tid];
    float4 pa1 = pac[tid + 256];
    float4 pa2 = pac[tid + 512];
    float4 pa3 = pac[tid + 768];

    // ---- lane-local max ----
    float m0 = fmaxf(fmaxf(v0.x, v0.y), fmaxf(v0.z, v0.w));
    float m1 = fmaxf(fmaxf(v1.x, v1.y), fmaxf(v1.z, v1.w));
    float m2 = fmaxf(fmaxf(v2.x, v2.y), fmaxf(v2.z, v2.w));
    float m3 = fmaxf(fmaxf(v3.x, v3.y), fmaxf(v3.z, v3.w));
    const float mlane = fmaxf(fmaxf(m0, m1), fmaxf(m2, m3));

    // wave max (LDS/shfl pipe) overlaps the exp pass (trans pipe)
    const float mw = wave_max(mlane);

    // e_j = exp(o_j - m_lane) in place; lane-relative sum
    float s = (exp4(v0, mlane) + exp4(v1, mlane)) +
              (exp4(v2, mlane) + exp4(v3, mlane));

    // rebase once to wave max, then plain sum-reduce
    float S_w = wave_sum(s * __expf(mlane - mw));
    if (lane0) red_ms[w] = make_float2(mw, S_w);
    __syncthreads();

    // cross-wave merge: max tree + 4 parallel exps (uniform on all threads)
    const float M = fmaxf(fmaxf(red_ms[0].x, red_ms[1].x),
                          fmaxf(red_ms[2].x, red_ms[3].x));
    const float S = red_ms[0].y * __expf(red_ms[0].x - M)
                  + red_ms[1].y * __expf(red_ms[1].x - M)
                  + red_ms[2].y * __expf(red_ms[2].x - M)
                  + red_ms[3].y * __expf(red_ms[3].x - M);
    const float L       = M + __logf(S);                 // true logsumexp
    const float logclip = fmaxf(o_t - L, LOG_EPS);       // log(max(p_t, EPS))
    const float Koff    = L + logclip;                   // g_j = exp(o_j - Koff)

    const float c  = __expf(mlane - Koff);               // g_j = e_j * c
    const float rt = __fdividef(1.0f, pa_t);

    // ---- pass 3: pure-VALU seesaw terms, 4 independent accumulators ----
    float z0 = zsum4(v0, pa0, rt, c);
    float z1 = zsum4(v1, pa1, rt, c);
    float z2 = zsum4(v2, pa2, rt, c);
    float z3 = zsum4(v3, pa3, rt, c);
    float z  = wave_sum((z0 + z1) + (z2 + z3));
    if (lane0) red_z[w] = z;
    __syncthreads();

    if (tid == 0) {
        float Z = (red_z[0] + red_z[1]) + (red_z[2] + red_z[3]);
        nll[b] = Koff + __logf(Z) - o_t;       // plain store, no atomics
    }
}

// deterministic final mean: fixed strided partials + fixed tree
__global__ __launch_bounds__(1024) void k_reduce(const float* __restrict__ nll,
                                                 float* __restrict__ out, int B) {
    __shared__ float red[16];
    const int tid = threadIdx.x;
    const float4* __restrict__ n4 = (const float4*)nll;
    float s = 0.f;
    for (int i = tid; i < B / 4; i += 1024) {
        float4 v = n4[i];
        s += (v.x + v.y) + (v.z + v.w);
    }
    s = wave_sum(s);
    if ((tid & 63) == 0) red[tid >> 6] = s;
    __syncthreads();
    if (tid == 0) {
        float tsum = 0.f;
        #pragma unroll
        for (int k = 0; k < 16; ++k) tsum += red[k];
        out[0] = tsum / (float)B;
    }
}

extern "C" void kernel_launch(void* const* d_in, const int* in_sizes, int n_in,
                              void* d_out, int out_size, void* d_ws, size_t ws_size,
                              hipStream_t stream) {
    const float* outp = (const float*)d_in[0];   // [B, C] f32
    const int*   tg   = (const int*)d_in[1];     // [B] i32
    float*       out  = (float*)d_out;           // scalar f32

    const int B = in_sizes[1];                   // 8192 (C fixed at 4096)

    char*  ws     = (char*)d_ws;
    float* powacc = (float*)ws;                  // 16 KB
    float* nll    = (float*)(ws + 16384);        // B*4 = 32 KB

    k_hist  <<<1, 1024, 0, stream>>>(tg, B, powacc);
    k_row   <<<B, 256, 0, stream>>>(outp, tg, powacc, nll);
    k_reduce<<<1, 1024, 0, stream>>>(nll, out, B);
}